// Round 1
// baseline (274.320 us; speedup 1.0000x reference)
//
#include <hip/hip_runtime.h>
#include <hip/hip_fp16.h>

// Problem constants (DCN: B=4, C=64, H=W=128, Cout=64, 3x3, pad=1, stride=1)
#define B_   4
#define C_   64
#define H_   128
#define W_   128
#define OC_  64
#define K_   9
#define OCH_ 18          // offset channels = 2*K
#define CK_  576         // C_*K_

// workspace layout (floats)
#define OFFS_ELEMS (B_*OCH_*H_*W_)   // 1179648
#define WT_OFFSET  OFFS_ELEMS        // wT: CK_*OC_ = 36864 floats

// ---------------------------------------------------------------------------
// k0: transpose main conv weight [oc][c][kh][kw] -> wT[ck][oc]
// ---------------------------------------------------------------------------
__global__ void k0_transpose_w(const float* __restrict__ weight,
                               float* __restrict__ wT) {
    int i = blockIdx.x * 256 + threadIdx.x;
    if (i >= CK_ * OC_) return;
    int oc = i & 63;
    int ck = i >> 6;
    wT[i] = weight[oc * CK_ + ck];
}

// ---------------------------------------------------------------------------
// k1: offset conv.  Block per (b, ho): 128 wo x 18 oc outputs.
// thread t: wo = t&127, half = t>>7 (oc = half*9 + j).
// LDS: full offset weight re-laid as [c][k][half][12] (9 used, float4-aligned),
//      x chunk [8][3][130].
// ---------------------------------------------------------------------------
__global__ __launch_bounds__(256) void k1_offset_conv(
    const float* __restrict__ x, const float* __restrict__ ow,
    const float* __restrict__ ob, float* __restrict__ offs)
{
    __shared__ __align__(16) float w2[C_ * K_ * 2 * 12];  // 55296 B
    __shared__ float xs[8 * 3 * 130];                      // 12480 B

    const int t  = threadIdx.x;
    const int b  = blockIdx.x >> 7;
    const int ho = blockIdx.x & 127;

    // stage offset weights: ow[oc][c][k] -> w2[c][k][half][j]
    for (int i = t; i < C_ * K_ * OCH_; i += 256) {
        int c  = i / 162;          // 162 = 9*18
        int r  = i - c * 162;
        int k  = r / 18;
        int oc = r - k * 18;
        int half = oc / 9, j = oc - half * 9;
        w2[((c * 9 + k) * 2 + half) * 12 + j] = ow[(oc * C_ + c) * K_ + k];
    }

    const int wo   = t & 127;
    const int half = t >> 7;
    float acc[9];
#pragma unroll
    for (int j = 0; j < 9; j++) acc[j] = 0.f;

    const float* xb = x + ((long)b << 20);   // b * 64*128*128

    for (int cc = 0; cc < C_; cc += 8) {
        __syncthreads();
        // stage x rows ho-1..ho+1 for 8 channels, width halo 130
        for (int i = t; i < 8 * 3 * 130; i += 256) {
            int c   = i / 390;
            int r   = i - c * 390;
            int row = r / 130;
            int col = r - row * 130;
            int gy = ho - 1 + row;
            int gx = col - 1;
            float v = 0.f;
            if (gy >= 0 && gy < H_ && gx >= 0 && gx < W_)
                v = xb[((cc + c) << 14) + (gy << 7) + gx];
            xs[i] = v;
        }
        __syncthreads();
#pragma unroll
        for (int c = 0; c < 8; c++) {
            float xv[9];
#pragma unroll
            for (int r = 0; r < 3; r++)
#pragma unroll
                for (int s = 0; s < 3; s++)
                    xv[r * 3 + s] = xs[c * 390 + r * 130 + wo + s];
#pragma unroll
            for (int k = 0; k < 9; k++) {
                const float* wp = &w2[(((cc + c) * 9 + k) * 2 + half) * 12];
                float4 wa = *(const float4*)wp;
                float4 wb = *(const float4*)(wp + 4);
                float  w8 = wp[8];
                float xk = xv[k];
                acc[0] += xk * wa.x; acc[1] += xk * wa.y;
                acc[2] += xk * wa.z; acc[3] += xk * wa.w;
                acc[4] += xk * wb.x; acc[5] += xk * wb.y;
                acc[6] += xk * wb.z; acc[7] += xk * wb.w;
                acc[8] += xk * w8;
            }
        }
    }

#pragma unroll
    for (int j = 0; j < 9; j++) {
        int oc = half * 9 + j;
        offs[((b * OCH_ + oc) * H_ + ho) * W_ + wo] = acc[j] + ob[oc];
    }
}

// ---------------------------------------------------------------------------
// k2: fused bilinear sampling + main conv.  Block per (b, ho): 128 pix x 64 oc.
// Phase A: bilinear meta for 9k x 128pix (packed idx + half2 weights, validity
//          folded into zeroed weights).
// Phase B: per 8-channel chunk: stage W[72][64] + sample P[72][128] into LDS,
//          then MAC with 4oc x 8pix register tiles.
// LDS total = 9216+9216+18432+36864 = 73728 B -> 2 blocks/CU.
// ---------------------------------------------------------------------------
__global__ __launch_bounds__(256) void k2_main(
    const float* __restrict__ x, const float* __restrict__ wT,
    const float* __restrict__ bias, const float* __restrict__ offs,
    float* __restrict__ out)
{
    __shared__ unsigned meta_i0[K_ * 128];   // i00 | i01<<16
    __shared__ unsigned meta_i1[K_ * 128];   // i10 | i11<<16
    __shared__ __half2  meta_wa[K_ * 128];   // (w00, w01)
    __shared__ __half2  meta_wb[K_ * 128];   // (w10, w11)
    __shared__ __align__(16) float wl[72 * 64];
    __shared__ __align__(16) float P[72 * 128];

    const int t  = threadIdx.x;
    const int b  = blockIdx.x >> 7;
    const int ho = blockIdx.x & 127;
    const float* xb = x + ((long)b << 20);

    // ---- Phase A: bilinear metadata ----
    for (int i = t; i < K_ * 128; i += 256) {
        int k   = i >> 7;
        int pix = i & 127;
        float dy = offs[((b * OCH_ + 2 * k) * H_ + ho) * W_ + pix];
        float dx = offs[((b * OCH_ + 2 * k + 1) * H_ + ho) * W_ + pix];
        int ky = k / 3;
        int kx = k - ky * 3;
        float py = (float)(ho - 1 + ky) + dy;
        float px = (float)(pix - 1 + kx) + dx;
        float fy = floorf(py), fx = floorf(px);
        float ly = py - fy, lx = px - fx;
        int y0 = (int)fy, x0 = (int)fx;
        int y1 = y0 + 1, x1 = x0 + 1;
        float vy0 = (y0 >= 0 && y0 < H_) ? 1.f : 0.f;
        float vy1 = (y1 >= 0 && y1 < H_) ? 1.f : 0.f;
        float vx0 = (x0 >= 0 && x0 < W_) ? 1.f : 0.f;
        float vx1 = (x1 >= 0 && x1 < W_) ? 1.f : 0.f;
        float w00 = (1.f - ly) * (1.f - lx) * vy0 * vx0;
        float w01 = (1.f - ly) * lx         * vy0 * vx1;
        float w10 = ly * (1.f - lx)         * vy1 * vx0;
        float w11 = ly * lx                 * vy1 * vx1;
        int cy0 = min(max(y0, 0), H_ - 1), cy1 = min(max(y1, 0), H_ - 1);
        int cx0 = min(max(x0, 0), W_ - 1), cx1 = min(max(x1, 0), W_ - 1);
        unsigned i00 = (unsigned)(cy0 * W_ + cx0);
        unsigned i01 = (unsigned)(cy0 * W_ + cx1);
        unsigned i10 = (unsigned)(cy1 * W_ + cx0);
        unsigned i11 = (unsigned)(cy1 * W_ + cx1);
        meta_i0[i] = i00 | (i01 << 16);
        meta_i1[i] = i10 | (i11 << 16);
        meta_wa[i] = __floats2half2_rn(w00, w01);
        meta_wb[i] = __floats2half2_rn(w10, w11);
    }

    const int oc_g  = t & 15;   // oc  = oc_g*4 .. +3
    const int pix_g = t >> 4;   // pix = pix_g*8 .. +7
    float acc[4][8];
#pragma unroll
    for (int j = 0; j < 4; j++) {
        float bv = bias[oc_g * 4 + j];
#pragma unroll
        for (int p = 0; p < 8; p++) acc[j][p] = bv;
    }

    // ---- Phase B: chunks of 8 input channels (72 ck each) ----
    for (int cc = 0; cc < C_; cc += 8) {
        __syncthreads();   // also covers Phase-A completion on first iter
        // stage weight chunk (coalesced from wT)
        for (int i = t; i < 72 * 64; i += 256)
            wl[i] = wT[cc * 9 * 64 + i];
        // sample patches P[ckl][pix]
        for (int i = t; i < 72 * 128; i += 256) {
            int ckl = i >> 7;
            int pix = i & 127;
            int c = ckl / 9;
            int k = ckl - c * 9;
            int mi = (k << 7) + pix;
            unsigned ia = meta_i0[mi];
            unsigned ib = meta_i1[mi];
            float2 w01v = __half22float2(meta_wa[mi]);
            float2 w23v = __half22float2(meta_wb[mi]);
            const float* xc = xb + ((cc + c) << 14);
            float v00 = xc[ia & 0xffffu];
            float v01 = xc[ia >> 16];
            float v10 = xc[ib & 0xffffu];
            float v11 = xc[ib >> 16];
            P[i] = v00 * w01v.x + v01 * w01v.y + v10 * w23v.x + v11 * w23v.y;
        }
        __syncthreads();
        // MAC: 72 ck, 4oc x 8pix register tile
#pragma unroll 2
        for (int ck = 0; ck < 72; ck++) {
            float4 wv = *(const float4*)&wl[(ck << 6) + (oc_g << 2)];
            float4 p0 = *(const float4*)&P[(ck << 7) + (pix_g << 3)];
            float4 p1 = *(const float4*)&P[(ck << 7) + (pix_g << 3) + 4];
            float wj[4] = {wv.x, wv.y, wv.z, wv.w};
            float pv[8] = {p0.x, p0.y, p0.z, p0.w, p1.x, p1.y, p1.z, p1.w};
#pragma unroll
            for (int j = 0; j < 4; j++)
#pragma unroll
                for (int p = 0; p < 8; p++)
                    acc[j][p] += wj[j] * pv[p];
        }
    }

    // ---- write out ----
#pragma unroll
    for (int j = 0; j < 4; j++) {
        int oc = oc_g * 4 + j;
        float* op = out + (((long)(b * OC_ + oc) * H_ + ho) * W_) + (pix_g << 3);
        float4 s0 = {acc[j][0], acc[j][1], acc[j][2], acc[j][3]};
        float4 s1 = {acc[j][4], acc[j][5], acc[j][6], acc[j][7]};
        *(float4*)op = s0;
        *(float4*)(op + 4) = s1;
    }
}

// ---------------------------------------------------------------------------
extern "C" void kernel_launch(void* const* d_in, const int* in_sizes, int n_in,
                              void* d_out, int out_size, void* d_ws, size_t ws_size,
                              hipStream_t stream) {
    const float* x   = (const float*)d_in[0];
    const float* w   = (const float*)d_in[1];
    const float* bi  = (const float*)d_in[2];
    const float* ow  = (const float*)d_in[3];
    const float* ob  = (const float*)d_in[4];
    float* out  = (float*)d_out;
    float* offs = (float*)d_ws;
    float* wT   = (float*)d_ws + WT_OFFSET;

    k0_transpose_w<<<(CK_ * OC_ + 255) / 256, 256, 0, stream>>>(w, wT);
    k1_offset_conv<<<B_ * H_, 256, 0, stream>>>(x, ow, ob, offs);
    k2_main<<<B_ * H_, 256, 0, stream>>>(x, wT, bi, offs, out);
}

// Round 2
// 222.768 us; speedup vs baseline: 1.2314x; 1.2314x over previous
//
#include <hip/hip_runtime.h>

// DCN: B=4, C=64, H=W=128, Cout=64, 3x3, pad=1, stride=1, dil=1
#define B_   4
#define C_   64
#define H_   128
#define W_   128
#define OC_  64
#define K_   9
#define OCH_ 18
#define CK_  576

#define S_   104              // LDS row stride in halfs (208 B: 16B-aligned rows)
#define SD_  (S_/2)           // 52 dwords
#define WCOLS 768             // 8 chunks * 96 padded cols

// ws layout (float units)
#define OFFS_ELEMS (B_*OCH_*H_*W_)          // 1179648 floats
#define WPAD_HALFS (OC_*WCOLS)              // 49152 halfs
#define W0PAD_HALFS (32*WCOLS)              // 24576 halfs

using half8v  = __attribute__((ext_vector_type(8))) _Float16;
using half2v  = __attribute__((ext_vector_type(2))) _Float16;
using float4v = __attribute__((ext_vector_type(4))) float;

// ---------------------------------------------------------------------------
// k0: cast+pad weights to f16 in MFMA-chunk layout.
// col = cc*96 + kk*8 + cl  (channel c = cc*8+cl, kernel idx kk; kk>=9 -> 0)
// ---------------------------------------------------------------------------
__global__ void k0_prep(const float* __restrict__ w, const float* __restrict__ ow,
                        _Float16* __restrict__ wpad, _Float16* __restrict__ w0pad) {
    int i = blockIdx.x * 256 + threadIdx.x;
    if (i < OC_ * WCOLS) {
        int oc = i / WCOLS, col = i - oc * WCOLS;
        int cc = col / 96, r = col - cc * 96;
        int kk = r >> 3, cl = r & 7;
        float v = 0.f;
        if (kk < 9) v = w[oc * CK_ + (cc * 8 + cl) * 9 + kk];
        wpad[i] = (_Float16)v;
    } else {
        int j = i - OC_ * WCOLS;
        if (j < 32 * WCOLS) {
            int rr = j / WCOLS, col = j - rr * WCOLS;
            int cc = col / 96, r = col - cc * 96;
            int kk = r >> 3, cl = r & 7;
            float v = 0.f;
            if (rr < OCH_ && kk < 9) v = ow[rr * CK_ + (cc * 8 + cl) * 9 + kk];
            w0pad[j] = (_Float16)v;
        }
    }
}

// ---------------------------------------------------------------------------
// k1: offset conv as f16 MFMA GEMM.  Block = (b, ho, half): out 18(x32)x64.
// P0 = plain im2col patches [pix][col], col = kk*8 + cl.
// ---------------------------------------------------------------------------
__global__ __launch_bounds__(256, 4) void k1_offset_conv(
    const float* __restrict__ x, const _Float16* __restrict__ w0pad,
    const float* __restrict__ ob, float* __restrict__ offs)
{
    __shared__ _Float16 W0l[32 * S_];
    __shared__ _Float16 P0l[64 * S_];

    const int t    = threadIdx.x;
    const int bid  = blockIdx.x;
    const int hb   = bid & 1;
    const int ho   = (bid >> 1) & 127;
    const int b    = bid >> 8;
    const int lane = t & 63;
    const int w    = t >> 6;
    const int po   = hb * 64 + lane;
    const float* xb = x + ((long)b << 20);

    // zero-pad P0l cols 72..95 once
    for (int i = t; i < 64 * 12; i += 256) {
        int row = i / 12, j = i - row * 12;
        *(unsigned*)&P0l[row * S_ + 72 + 2 * j] = 0u;
    }

    float4v acc0 = {0.f, 0.f, 0.f, 0.f};
    float4v acc1 = {0.f, 0.f, 0.f, 0.f};
    const int lr = lane & 15, q = lane >> 4;

    for (int cc = 0; cc < 8; cc++) {
        if (cc) __syncthreads();
        // stage W0 chunk: 32 rows x 48 dwords
        const unsigned* wsrc = (const unsigned*)w0pad;
        for (int i = t; i < 32 * 48; i += 256) {
            int oc = i / 48, cd = i - oc * 48;
            ((unsigned*)W0l)[oc * SD_ + cd] = wsrc[oc * (WCOLS / 2) + cc * 48 + cd];
        }
        // im2col: wave w -> channels (2w, 2w+1)
        const int c0 = cc * 8 + 2 * w;
        const float* xc0 = xb + ((long)c0 << 14);
        const float* xc1 = xc0 + (1 << 14);
#pragma unroll
        for (int kk = 0; kk < 9; kk++) {
            const int ky = kk / 3, kx = kk - ky * 3;
            const int gy = ho - 1 + ky;
            const int gx = po - 1 + kx;
            const bool ok = (gy >= 0) && (gy < H_) && (gx >= 0) && (gx < W_);
            float v0 = 0.f, v1 = 0.f;
            if (ok) {
                int idx = (gy << 7) + gx;
                v0 = xc0[idx];
                v1 = xc1[idx];
            }
            half2v hv = {(_Float16)v0, (_Float16)v1};
            *(half2v*)&P0l[lane * S_ + kk * 8 + 2 * w] = hv;
        }
        __syncthreads();
        // MFMA: wave w = pix tile nt=w; mt 0..1
#pragma unroll
        for (int ks = 0; ks < 3; ks++) {
            half8v a0 = *(const half8v*)&W0l[lr * S_ + ks * 32 + q * 8];
            half8v a1 = *(const half8v*)&W0l[(16 + lr) * S_ + ks * 32 + q * 8];
            half8v bv = *(const half8v*)&P0l[(w * 16 + lr) * S_ + ks * 32 + q * 8];
            acc0 = __builtin_amdgcn_mfma_f32_16x16x32_f16(a0, bv, acc0, 0, 0, 0);
            acc1 = __builtin_amdgcn_mfma_f32_16x16x32_f16(a1, bv, acc1, 0, 0, 0);
        }
    }

    // epilogue: rows = mt*16 + q*4 + r (keep <18), col pix = hb*64 + w*16 + lr
    const int pix = hb * 64 + w * 16 + lr;
#pragma unroll
    for (int r = 0; r < 4; r++) {
        int ch = q * 4 + r;
        offs[(((b * OCH_ + ch) << 7) + ho << 7) + pix] = acc0[r] + ob[ch];
    }
#pragma unroll
    for (int r = 0; r < 4; r++) {
        int ch = 16 + q * 4 + r;
        if (ch < OCH_)
            offs[(((b * OCH_ + ch) << 7) + ho << 7) + pix] = acc1[r] + ob[ch];
    }
}

// ---------------------------------------------------------------------------
// k2: fused bilinear sampling + main conv as f16 MFMA GEMM.
// Block = (b, ho, half): out 64oc x 64pix, K = 8 chunks x 96 (72 real).
// Bilinear meta per thread in registers (9 k's for its pixel).
// ---------------------------------------------------------------------------
__global__ __launch_bounds__(256, 4) void k2_main(
    const float* __restrict__ x, const _Float16* __restrict__ wpad,
    const float* __restrict__ bias, const float* __restrict__ offs,
    float* __restrict__ out)
{
    __shared__ _Float16 Wl[64 * S_];
    __shared__ _Float16 Pl[64 * S_];

    const int t    = threadIdx.x;
    const int bid  = blockIdx.x;
    const int hb   = bid & 1;
    const int ho   = (bid >> 1) & 127;
    const int b    = bid >> 8;
    const int lane = t & 63;
    const int w    = t >> 6;
    const int po   = hb * 64 + lane;
    const float* xb = x + ((long)b << 20);

    // ---- per-thread bilinear meta for 9 kernel taps at pixel po ----
    int   ma0[9], ma1[9];
    float mw[9][4];
#pragma unroll
    for (int kk = 0; kk < 9; kk++) {
        const int ky = kk / 3, kx = kk - ky * 3;
        float dy = offs[((b * OCH_ + 2 * kk) << 14) + (ho << 7) + po];
        float dx = offs[((b * OCH_ + 2 * kk + 1) << 14) + (ho << 7) + po];
        float py = (float)(ho - 1 + ky) + dy;
        float px = (float)(po - 1 + kx) + dx;
        float fy = floorf(py), fx = floorf(px);
        float ly = py - fy, lx = px - fx;
        int y0 = (int)fy, x0 = (int)fx;
        int y1 = y0 + 1, x1 = x0 + 1;
        float vy0 = ((unsigned)y0 < (unsigned)H_) ? 1.f : 0.f;
        float vy1 = ((unsigned)y1 < (unsigned)H_) ? 1.f : 0.f;
        float vx0 = ((unsigned)x0 < (unsigned)W_) ? 1.f : 0.f;
        float vx1 = ((unsigned)x1 < (unsigned)W_) ? 1.f : 0.f;
        float w00 = (1.f - ly) * (1.f - lx) * vy0 * vx0;
        float w01 = (1.f - ly) * lx * vy0 * vx1;
        float w10 = ly * (1.f - lx) * vy1 * vx0;
        float w11 = ly * lx * vy1 * vx1;
        int cy0 = min(max(y0, 0), H_ - 1);
        int cy1 = min(max(y1, 0), H_ - 1);
        int xl  = min(max(x0, 0), W_ - 2);
        // fold x-clamp into weight swap: pair load at (cy, xl), (cy, xl+1)
        bool noswap = (x0 == xl);
        mw[kk][0] = noswap ? w00 : w01;
        mw[kk][1] = noswap ? w01 : w00;
        mw[kk][2] = noswap ? w10 : w11;
        mw[kk][3] = noswap ? w11 : w10;
        ma0[kk] = (cy0 << 7) + xl;
        ma1[kk] = (cy1 << 7) + xl;
    }

    // zero-pad Pl cols 72..95 once
    for (int i = t; i < 64 * 12; i += 256) {
        int row = i / 12, j = i - row * 12;
        *(unsigned*)&Pl[row * S_ + 72 + 2 * j] = 0u;
    }

    float4v acc00 = {0.f,0.f,0.f,0.f}, acc01 = {0.f,0.f,0.f,0.f};
    float4v acc10 = {0.f,0.f,0.f,0.f}, acc11 = {0.f,0.f,0.f,0.f};
    const int lr = lane & 15, q = lane >> 4;
    const int wm = w & 1, wn = w >> 1;

    for (int cc = 0; cc < 8; cc++) {
        if (cc) __syncthreads();
        // stage W chunk: 64 rows x 48 dwords (f16, zero-padded cols built by k0)
        const unsigned* wsrc = (const unsigned*)wpad;
        for (int i = t; i < 64 * 48; i += 256) {
            int oc = i / 48, cd = i - oc * 48;
            ((unsigned*)Wl)[oc * SD_ + cd] = wsrc[oc * (WCOLS / 2) + cc * 48 + cd];
        }
        // sampling: wave w -> channels (2w, 2w+1)
        const int c0 = cc * 8 + 2 * w;
        const float* xc0 = xb + ((long)c0 << 14);
        const float* xc1 = xc0 + (1 << 14);
#pragma unroll
        for (int kk = 0; kk < 9; kk++) {
            const int a0 = ma0[kk], a1 = ma1[kk];
            float s00 = xc0[a0], s01 = xc0[a0 + 1];
            float s10 = xc0[a1], s11 = xc0[a1 + 1];
            float t00 = xc1[a0], t01 = xc1[a0 + 1];
            float t10 = xc1[a1], t11 = xc1[a1 + 1];
            float p0 = s00 * mw[kk][0] + s01 * mw[kk][1] + s10 * mw[kk][2] + s11 * mw[kk][3];
            float p1 = t00 * mw[kk][0] + t01 * mw[kk][1] + t10 * mw[kk][2] + t11 * mw[kk][3];
            half2v hv = {(_Float16)p0, (_Float16)p1};
            *(half2v*)&Pl[lane * S_ + kk * 8 + 2 * w] = hv;
        }
        __syncthreads();
        // MFMA: wave (wm, wn) -> oc 32-slab x pix 32-slab, 2x2 tiles of 16x16
#pragma unroll
        for (int ks = 0; ks < 3; ks++) {
            half8v a0 = *(const half8v*)&Wl[(wm * 32 + lr) * S_ + ks * 32 + q * 8];
            half8v a1 = *(const half8v*)&Wl[(wm * 32 + 16 + lr) * S_ + ks * 32 + q * 8];
            half8v b0 = *(const half8v*)&Pl[(wn * 32 + lr) * S_ + ks * 32 + q * 8];
            half8v b1 = *(const half8v*)&Pl[(wn * 32 + 16 + lr) * S_ + ks * 32 + q * 8];
            acc00 = __builtin_amdgcn_mfma_f32_16x16x32_f16(a0, b0, acc00, 0, 0, 0);
            acc01 = __builtin_amdgcn_mfma_f32_16x16x32_f16(a0, b1, acc01, 0, 0, 0);
            acc10 = __builtin_amdgcn_mfma_f32_16x16x32_f16(a1, b0, acc10, 0, 0, 0);
            acc11 = __builtin_amdgcn_mfma_f32_16x16x32_f16(a1, b1, acc11, 0, 0, 0);
        }
    }

    // epilogue
    const int pixc = hb * 64 + wn * 32 + lr;   // col within tile nt=0
#pragma unroll
    for (int r = 0; r < 4; r++) {
        int oc0 = wm * 32 + q * 4 + r;
        int oc1 = oc0 + 16;
        float* o0 = out + (((long)(b * OC_ + oc0)) << 14) + (ho << 7);
        float* o1 = out + (((long)(b * OC_ + oc1)) << 14) + (ho << 7);
        o0[pixc]      = acc00[r] + bias[oc0];
        o0[pixc + 16] = acc01[r] + bias[oc0];
        o1[pixc]      = acc10[r] + bias[oc1];
        o1[pixc + 16] = acc11[r] + bias[oc1];
    }
}

// ---------------------------------------------------------------------------
extern "C" void kernel_launch(void* const* d_in, const int* in_sizes, int n_in,
                              void* d_out, int out_size, void* d_ws, size_t ws_size,
                              hipStream_t stream) {
    const float* x  = (const float*)d_in[0];
    const float* wt = (const float*)d_in[1];
    const float* bi = (const float*)d_in[2];
    const float* ow = (const float*)d_in[3];
    const float* ob = (const float*)d_in[4];
    float* out  = (float*)d_out;

    float*     offs  = (float*)d_ws;
    _Float16*  wpad  = (_Float16*)((float*)d_ws + OFFS_ELEMS);
    _Float16*  w0pad = wpad + WPAD_HALFS;

    k0_prep<<<(OC_ * WCOLS + 32 * WCOLS + 255) / 256, 256, 0, stream>>>(wt, ow, wpad, w0pad);
    k1_offset_conv<<<B_ * H_ * 2, 256, 0, stream>>>(x, w0pad, ob, offs);
    k2_main<<<B_ * H_ * 2, 256, 0, stream>>>(x, wpad, bi, offs, out);
}